// Round 2
// baseline (267.250 us; speedup 1.0000x reference)
//
#include <hip/hip_runtime.h>

// Problem constants (fixed by setup_inputs in the reference)
constexpr int B = 128;
constexpr int C = 4;          // classes; C*S = 2^18
constexpr int S = 65536;      // 2^16
constexpr int N = B * S;      // 8388608 positions
constexpr int NG = N / 4;     // float4 groups = 2097152
constexpr int NSEG = 8;
constexpr int NACC = 2 * NSEG + 1;  // 17: 8 seg sums, 8 seg counts, 1 mask sum

constexpr int GRID = 2048;
constexpr int BLOCK = 256;
constexpr int ITERS = NG / (GRID * BLOCK);   // exactly 4
static_assert(ITERS * GRID * BLOCK == NG, "grid must tile NG exactly");

// ws layout: pt[i * GRID + b] = block b's partial for accumulator i (column-major
// so the stage-2 reduction reads coalesced). 2048*17*4 = 139264 bytes.

__global__ __launch_bounds__(BLOCK) void ce_partial_kernel(
    const float* __restrict__ input,   // (B, C, S)
    const int*   __restrict__ target,  // (B, S) values in [0, C)
    const int*   __restrict__ seg,     // (B, S) values in [0, NSEG)
    const float* __restrict__ mask,    // (B, S) in {0,1}
    float* __restrict__ pt)            // (NACC, GRID) partials
{
    float ssum[NSEG], scnt[NSEG];
#pragma unroll
    for (int k = 0; k < NSEG; ++k) { ssum[k] = 0.f; scnt[k] = 0.f; }
    float msum = 0.f;

    const int tid = blockIdx.x * BLOCK + threadIdx.x;
#pragma unroll
    for (int it = 0; it < ITERS; ++it) {
        const int g = tid + it * (GRID * BLOCK);
        const int p = g << 2;             // flat position (b*S + s), 4-aligned
        const int b = p >> 16;            // p / S
        const int s = p & (S - 1);
        const int base = (b << 18) + s;   // b*C*S + s

        const float4 l0 = *(const float4*)(input + base);
        const float4 l1 = *(const float4*)(input + base + S);
        const float4 l2 = *(const float4*)(input + base + 2 * S);
        const float4 l3 = *(const float4*)(input + base + 3 * S);
        const int4   tg = *(const int4*)(target + p);
        const int4   sv = *(const int4*)(seg + p);
        const float4 mk = *(const float4*)(mask + p);

        const float a0[4] = { l0.x, l0.y, l0.z, l0.w };
        const float a1[4] = { l1.x, l1.y, l1.z, l1.w };
        const float a2[4] = { l2.x, l2.y, l2.z, l2.w };
        const float a3[4] = { l3.x, l3.y, l3.z, l3.w };
        const int   tgv[4] = { tg.x, tg.y, tg.z, tg.w };
        const int   sgv[4] = { sv.x, sv.y, sv.z, sv.w };
        const float mkv[4] = { mk.x, mk.y, mk.z, mk.w };

#pragma unroll
        for (int j = 0; j < 4; ++j) {
            const float x0 = a0[j], x1 = a1[j], x2 = a2[j], x3 = a3[j];
            const float m = fmaxf(fmaxf(x0, x1), fmaxf(x2, x3));
            const float sum = __expf(x0 - m) + __expf(x1 - m)
                            + __expf(x2 - m) + __expf(x3 - m);
            const float lse = m + __logf(sum);
            const int t = tgv[j];
            const float chosen = (t == 0) ? x0 : (t == 1) ? x1 : (t == 2) ? x2 : x3;
            const float mval = mkv[j];
            const float loss = (lse - chosen) * mval;   // ce * mask
            const float v = (mval > 0.f) ? 1.f : 0.f;   // valid
            const int sgj = sgv[j];
            msum += mval;
            // Predicated accumulation: avoids dynamic register indexing
#pragma unroll
            for (int k = 0; k < NSEG; ++k) {
                const bool hit = (sgj == k);
                ssum[k] += hit ? loss : 0.f;
                scnt[k] += hit ? v : 0.f;
            }
        }
    }

    // Wave (64-lane) butterfly reduction of all 17 accumulators
    float vals[NACC];
#pragma unroll
    for (int k = 0; k < NSEG; ++k) { vals[k] = ssum[k]; vals[NSEG + k] = scnt[k]; }
    vals[16] = msum;
#pragma unroll
    for (int i = 0; i < NACC; ++i) {
        float v = vals[i];
#pragma unroll
        for (int off = 32; off > 0; off >>= 1)
            v += __shfl_xor(v, off, 64);
        vals[i] = v;
    }

    __shared__ float red[4][NACC];
    const int wave = threadIdx.x >> 6;
    const int lane = threadIdx.x & 63;
    if (lane == 0) {
#pragma unroll
        for (int i = 0; i < NACC; ++i) red[wave][i] = vals[i];
    }
    __syncthreads();
    // 17 plain stores per block to private slots — no atomics, no contention
    if (threadIdx.x < NACC) {
        const int i = threadIdx.x;
        pt[i * GRID + blockIdx.x] =
            red[0][i] + red[1][i] + red[2][i] + red[3][i];
    }
}

// Stage 2: reduce (NACC, GRID) partials and run the scalar epilogue. One block.
__global__ __launch_bounds__(1024) void ce_final_kernel(
    const float* __restrict__ pt, float* __restrict__ out)
{
    const int t = threadIdx.x;            // 1024 threads
    float vals[NACC];
#pragma unroll
    for (int i = 0; i < NACC; ++i) {
        // coalesced: consecutive threads read consecutive blocks' partials
        vals[i] = pt[i * GRID + t] + pt[i * GRID + t + 1024];
#pragma unroll
        for (int off = 32; off > 0; off >>= 1)
            vals[i] += __shfl_xor(vals[i], off, 64);
    }

    __shared__ float red[16][NACC];
    const int wave = t >> 6;
    const int lane = t & 63;
    if (lane == 0) {
#pragma unroll
        for (int i = 0; i < NACC; ++i) red[wave][i] = vals[i];
    }
    __syncthreads();

    if (t == 0) {
        float acc[NACC];
        for (int i = 0; i < NACC; ++i) {
            float v = 0.f;
            for (int w = 0; w < 16; ++w) v += red[w][i];
            acc[i] = v;
        }

        float ssum[NSEG], scnt[NSEG];
        float tot_loss = 0.f;
        for (int k = 0; k < NSEG; ++k) {
            ssum[k] = acc[k];
            scnt[k] = acc[NSEG + k];
            tot_loss += ssum[k];
        }
        const float msum = acc[16];
        const float fallback = tot_loss / (float)N;   // jnp.mean(loss)

        float cl[NSEG], cc[NSEG];
        float total = 0.f;
        for (int k = 0; k < NSEG; ++k) {
            const bool has = scnt[k] > 0.f;
            cl[k] = has ? (ssum[k] / scnt[k]) : fallback;
            cc[k] = has ? scnt[k] : 1.f;
            total += cl[k] * cc[k];
        }
        float num = 0.f;
        for (int k = 0; k < NSEG; ++k) {
            const float prop = (total > 0.f) ? (cl[k] * cc[k] / total)
                                             : (1.f / (float)NSEG);
            const float w = 1.f + prop;               // WEIGHT_ALPHA = 1.0
            // sum(loss * adaptive_weights) = sum_k w[k] * seg_sum[k]
            num += w * ssum[k];
        }
        out[0] = num / msum;                          // / sum(mask)
    }
}

extern "C" void kernel_launch(void* const* d_in, const int* in_sizes, int n_in,
                              void* d_out, int out_size, void* d_ws, size_t ws_size,
                              hipStream_t stream) {
    const float* input  = (const float*)d_in[0];
    const int*   target = (const int*)d_in[1];
    const int*   seg    = (const int*)d_in[2];
    const float* mask   = (const float*)d_in[3];
    float* pt  = (float*)d_ws;            // NACC * GRID floats = 139 KB
    float* out = (float*)d_out;

    ce_partial_kernel<<<GRID, BLOCK, 0, stream>>>(input, target, seg, mask, pt);
    ce_final_kernel<<<1, 1024, 0, stream>>>(pt, out);
}